// Round 9
// baseline (441.396 us; speedup 1.0000x reference)
//
#include <hip/hip_runtime.h>
#include <hip/hip_bf16.h>

// Fused Comm_OUT pipeline, batch-row-parallel (GRU recurrence is per-row).
// Round-15: NO-DRAIN BARRIER. r8 (2 independent barrier domains/CU) gave
// 411->360us. Remaining stall: __syncthreads() = s_waitcnt vmcnt(0)
// lgkmcnt(0) + s_barrier - every wave drains ~66 outstanding weight loads
// every step. For THIS kernel the vmcnt drain is semantically useless:
// globals are read-only weights + never-read out stores; the only
// cross-wave hazard is LDS (covered by lgkmcnt(0)). Replace the loop
// barrier with inline-asm {s_waitcnt lgkmcnt(0); s_barrier} so weight
// loads pipeline ACROSS steps (guide T4: never vmcnt(0) in the loop).
// Single-lever change vs r8 for clean attribution.
// 512 blocks x 512 threads (8 waves x 32 cols), BM=16, 2 blocks/CU.
// Runtime dtype detection (inputs fp32 or bf16) via g_flag.

typedef __attribute__((ext_vector_type(8))) short bf16x8;   // 8 x bf16 (4 VGPRs)
typedef __attribute__((ext_vector_type(4))) float f32x4;    // MFMA accumulator

#define MFMA16(a, b, c) __builtin_amdgcn_mfma_f32_16x16x32_bf16((a), (b), (c), 0, 0, 0)

// LDS-only barrier: no vmcnt drain (weights are read-only; out never read).
__device__ __forceinline__ void bar_nodrain() {
    asm volatile("s_waitcnt lgkmcnt(0)\n\ts_barrier" ::: "memory");
}

constexpr int F   = 640;
constexpr int H   = 256;
constexpr int LSTEPS = 20;
constexpr int CO  = 32;
constexpr int LDP = 264;   // padded bf16 row stride (16B-aligned rows)
constexpr int BM  = 16;    // rows per block (2 blocks/CU)

// packed-weight element offsets inside g_wpk (layout unchanged from r7)
constexpr size_t WHH_E  = 0;                    // 8cg*3g*8kk*2j*64lane*8 = 196608
constexpr size_t WIH_E  = 196608;               // 196608
constexpr size_t WC_E   = 393216;               // 8cg*8kk*2j*64*8       = 65536
constexpr size_t WMU_E  = 458752;               // 2w*8kk*64*8           = 8192
constexpr size_t WLIN_E = 466944;               // 8cg*20kk*2j*64*8      = 163840
constexpr size_t PK_ELEMS = 630784;

__device__ __align__(16) unsigned short g_wpk[PK_ELEMS];
__device__ int g_flag;     // 1 = inputs are fp32

__device__ __forceinline__ float bf2f(__hip_bfloat16 x) { return __bfloat162float(x); }
__device__ __forceinline__ float bfu(unsigned short s) {
    __hip_bfloat16 h = *reinterpret_cast<__hip_bfloat16*>(&s);
    return __bfloat162float(h);
}
__device__ __forceinline__ unsigned short f2bs(float f) {
    __hip_bfloat16 h = __float2bfloat16(f);
    return *reinterpret_cast<unsigned short*>(&h);
}
__device__ __forceinline__ bf16x8 lds8(const unsigned short* p) {
    return *reinterpret_cast<const bf16x8*>(p);
}
__device__ __forceinline__ bf16x8 pk8(size_t eoff) {
    return *reinterpret_cast<const bf16x8*>(g_wpk + eoff);
}
__device__ __forceinline__ float sigm(float x) {
    return 1.0f / (1.0f + __expf(-x));
}
__device__ __forceinline__ unsigned pack2(float lo, float hi) {
    return (unsigned)f2bs(lo) | ((unsigned)f2bs(hi) << 16);
}

template<bool F32>
__device__ __forceinline__ bf16x8 g8(const void* base, size_t off) {
    if constexpr (!F32) {
        return *reinterpret_cast<const bf16x8*>((const __hip_bfloat16*)base + off);
    } else {
        const float* f = (const float*)base + off;
        float4 lo = *reinterpret_cast<const float4*>(f);
        float4 hi = *reinterpret_cast<const float4*>(f + 4);
        bf16x8 r;
        r[0] = (short)f2bs(lo.x); r[1] = (short)f2bs(lo.y);
        r[2] = (short)f2bs(lo.z); r[3] = (short)f2bs(lo.w);
        r[4] = (short)f2bs(hi.x); r[5] = (short)f2bs(hi.y);
        r[6] = (short)f2bs(hi.z); r[7] = (short)f2bs(hi.w);
        return r;
    }
}

template<bool F32>
__device__ __forceinline__ float ld1(const void* base, int i) {
    if constexpr (!F32) return bf2f(((const __hip_bfloat16*)base)[i]);
    else                return ((const float*)base)[i];
}

// ---------------- dtype detect: v1 (uniform[0.5,1.5]) ----------------
__global__ void detect_dtype(const void* v1) {
    const unsigned short* u = (const unsigned short*)v1;
    int f32 = 0;
    for (int i = 0; i < 8; ++i) {
        unsigned short s = u[i];
        __hip_bfloat16 h = *reinterpret_cast<__hip_bfloat16*>(&s);
        float v = __bfloat162float(h);
        if (!(v >= 0.25f && v <= 2.0f)) f32 = 1;
    }
    g_flag = f32;
}

// ---------------- weight pre-pack (fp32|bf16 -> bf16 fragment streams) ----------------
__device__ __forceinline__ unsigned short cvt1(const void* p, size_t i, bool f32) {
    if (f32) return f2bs(((const float*)p)[i]);
    return ((const unsigned short*)p)[i];
}

__global__ void prepack(const void* Wlin, const void* Wih, const void* Whh,
                        const void* Wc, const void* Wmu) {
    const bool f32 = (g_flag != 0);
    const int gid = blockIdx.x * 256 + threadIdx.x;
    const void* src;
    size_t dbase;
    int row, col0, ncols;
    if (gid < 24576) {                       // Whh [768,256]
        int idx = gid;
        int lane = idx & 63, j = (idx >> 6) & 1, kk = (idx >> 7) & 7;
        int t2 = idx >> 10, g = t2 % 3, w = t2 / 3;
        row = g * 256 + w * 32 + j * 16 + (lane & 15);
        col0 = kk * 32 + (lane >> 4) * 8;
        ncols = 256; src = Whh; dbase = WHH_E + (size_t)idx * 8;
    } else if (gid < 49152) {                // Wih [768,256]
        int idx = gid - 24576;
        int lane = idx & 63, j = (idx >> 6) & 1, kk = (idx >> 7) & 7;
        int t2 = idx >> 10, g = t2 % 3, w = t2 / 3;
        row = g * 256 + w * 32 + j * 16 + (lane & 15);
        col0 = kk * 32 + (lane >> 4) * 8;
        ncols = 256; src = Wih; dbase = WIH_E + (size_t)idx * 8;
    } else if (gid < 57344) {                // Wc [256,256]
        int idx = gid - 49152;
        int lane = idx & 63, j = (idx >> 6) & 1, kk = (idx >> 7) & 7, w = idx >> 10;
        row = w * 32 + j * 16 + (lane & 15);
        col0 = kk * 32 + (lane >> 4) * 8;
        ncols = 256; src = Wc; dbase = WC_E + (size_t)idx * 8;
    } else if (gid < 58368) {                // Wmu [32,256]
        int idx = gid - 57344;
        int lane = idx & 63, kk = (idx >> 6) & 7, w = idx >> 9;
        row = w * 16 + (lane & 15);
        col0 = kk * 32 + (lane >> 4) * 8;
        ncols = 256; src = Wmu; dbase = WMU_E + (size_t)idx * 8;
    } else if (gid < 78848) {                // Wlin [256,640]
        int idx = gid - 58368;
        int lane = idx & 63, j = (idx >> 6) & 1;
        int t1 = idx >> 7, kk = t1 % 20, w = t1 / 20;
        row = w * 32 + j * 16 + (lane & 15);
        col0 = kk * 32 + (lane >> 4) * 8;
        ncols = 640; src = Wlin; dbase = WLIN_E + (size_t)idx * 8;
    } else {
        return;
    }
    const size_t s0 = (size_t)row * ncols + col0;
    #pragma unroll
    for (int i = 0; i < 8; ++i) g_wpk[dbase + i] = cvt1(src, s0 + i, f32);
}

// ---------------- FAST PATH: BM=16, 512 threads, 8 waves, 1 no-drain barrier/step ----------------
template<bool F32>
__device__ __forceinline__ void fast_pipe(
    const void* hw, const void* blin,
    const void* g1, const void* be1, const void* m1, const void* v1, const void* a1,
    const void* bih, const void* bhh,
    const void* g2, const void* be2, const void* m2, const void* v2, const void* a2,
    const void* bc,
    const void* g3, const void* be3, const void* m3, const void* v3, const void* a3,
    const void* bmu,
    void* out,
    unsigned short (*hb)[BM * LDP],
    unsigned short (*yb)[BM * LDP],
    unsigned short (*zb)[BM * LDP])
{
    const int tid  = threadIdx.x;
    const int cg   = tid >> 6;        // wave = 32-col group, 0..7
    const int lane = tid & 63;
    const int m16  = lane & 15;
    const int q    = lane >> 4;
    const int row0 = blockIdx.x * BM;
    const int c0 = cg * 32 + m16;
    const int c1 = c0 + 16;
    const int cc2[2] = { c0, c1 };
    const size_t lane8 = (size_t)lane * 8;

    // persistent per-step params (folded)
    float s2v[2], t2v[2], s3v[2], t3f[2], bhhn[2];
    #pragma unroll
    for (int j = 0; j < 2; ++j) {
        const int cc = cc2[j];
        float s;
        s = ld1<F32>(g2, cc) * rsqrtf(ld1<F32>(v2, cc) + 1e-5f);
        s2v[j] = s; t2v[j] = ld1<F32>(be2, cc) - ld1<F32>(m2, cc) * s;
        s = ld1<F32>(g3, cc) * rsqrtf(ld1<F32>(v3, cc) + 1e-5f);
        s3v[j] = s;
        t3f[j] = (ld1<F32>(bc, cc) - ld1<F32>(m3, cc)) * s + ld1<F32>(be3, cc);
        bhhn[j] = ld1<F32>(bhh, 2 * H + cc);
    }
    const float a2v = ld1<F32>(a2, 0), a3v = ld1<F32>(a3, 0);

    // ---- Phase 1: x = prelu(bn1(rows @ Wlin^T + blin)) -> yb[0] ----
    {
        f32x4 xacc[2] = {};   // [j]
        #pragma unroll 5
        for (int kk = 0; kk < F / 32; ++kk) {
            bf16x8 fa0 = g8<F32>(hw, (size_t)(row0 + m16) * F + kk * 32 + q * 8);
            bf16x8 b0 = pk8(WLIN_E + (size_t)((cg * 20 + kk) * 2 + 0) * 512 + lane8);
            bf16x8 b1 = pk8(WLIN_E + (size_t)((cg * 20 + kk) * 2 + 1) * 512 + lane8);
            xacc[0] = MFMA16(fa0, b0, xacc[0]);
            xacc[1] = MFMA16(fa0, b1, xacc[1]);
        }
        #pragma unroll
        for (int j = 0; j < 2; ++j) {
            const int cc = cc2[j];
            float s = ld1<F32>(g1, cc) * rsqrtf(ld1<F32>(v1, cc) + 1e-5f);
            float t = ld1<F32>(be1, cc) - ld1<F32>(m1, cc) * s;
            float bl = ld1<F32>(blin, cc);
            float av = ld1<F32>(a1, 0);
            #pragma unroll
            for (int r = 0; r < 4; ++r) {
                float vv = (xacc[j][r] + bl) * s + t;
                vv = (vv >= 0.0f) ? vv : av * vv;
                yb[0][(q * 4 + r) * LDP + cc] = f2bs(vv);
            }
        }
    }
    __syncthreads();   // x visible in yb[0] (once; drain harmless here)

    // ---- Phase 2: gi = x @ Wih^T + biases; r/z packed bf16, n kept f32 ----
    unsigned girz[2][4];   // [j][r]: lo = r-gate, hi = z-gate pre-act
    f32x4 gin[2];          // [j]: n-gate pre-act
    {
        f32x4 ga[3][2] = {};
        const unsigned short* xa0 = yb[0] + m16 * LDP + q * 8;
        #pragma unroll
        for (int kk = 0; kk < 8; ++kk) {
            bf16x8 fa0 = lds8(xa0 + kk * 32);
            #pragma unroll
            for (int g = 0; g < 3; ++g) {
                bf16x8 b0 = pk8(WIH_E + (size_t)(((cg * 3 + g) * 8 + kk) * 2 + 0) * 512 + lane8);
                bf16x8 b1 = pk8(WIH_E + (size_t)(((cg * 3 + g) * 8 + kk) * 2 + 1) * 512 + lane8);
                ga[g][0] = MFMA16(fa0, b0, ga[g][0]);
                ga[g][1] = MFMA16(fa0, b1, ga[g][1]);
            }
        }
        #pragma unroll
        for (int j = 0; j < 2; ++j) {
            const float br = ld1<F32>(bih, 0 * H + cc2[j]) + ld1<F32>(bhh, 0 * H + cc2[j]);
            const float bz = ld1<F32>(bih, 1 * H + cc2[j]) + ld1<F32>(bhh, 1 * H + cc2[j]);
            const float bn = ld1<F32>(bih, 2 * H + cc2[j]);
            #pragma unroll
            for (int r = 0; r < 4; ++r)
                girz[j][r] = pack2(ga[0][j][r] + br, ga[1][j][r] + bz);
            #pragma unroll
            for (int r = 0; r < 4; ++r) gin[j][r] = ga[2][j][r] + bn;
        }
    }
    __syncthreads();   // protects yb[0] for reuse as y(0) at iter 0

    // ---- GRU loop state ----
    unsigned short hs[2][4];
    #pragma unroll
    for (int j = 0; j < 2; ++j)
        #pragma unroll
        for (int r = 0; r < 4; ++r) hs[j][r] = 0;   // bf16 +0.0

    const int nto = cg & 1;   // for cg<2: output col tile
    const float bmuv = (cg < 2) ? ld1<F32>(bmu, nto * 16 + m16) : 0.0f;

    // --- phase lambdas (inlined; straight-line in the steady body) ---
    auto do_wc = [&](int prv) {
        f32x4 w2[2] = {};
        const unsigned short* ya0 = yb[prv] + m16 * LDP + q * 8;
        #pragma unroll
        for (int kk = 0; kk < 8; ++kk) {
            bf16x8 fa0 = lds8(ya0 + kk * 32);
            bf16x8 b0 = pk8(WC_E + (size_t)((cg * 8 + kk) * 2 + 0) * 512 + lane8);
            bf16x8 b1 = pk8(WC_E + (size_t)((cg * 8 + kk) * 2 + 1) * 512 + lane8);
            w2[0] = MFMA16(fa0, b0, w2[0]);
            w2[1] = MFMA16(fa0, b1, w2[1]);
        }
        #pragma unroll
        for (int j = 0; j < 2; ++j)
            #pragma unroll
            for (int r = 0; r < 4; ++r) {
                float z0 = w2[j][r] * s3v[j] + t3f[j];
                z0 = (z0 >= 0.0f) ? z0 : a3v * z0;
                zb[prv][(q * 4 + r) * LDP + cc2[j]] = f2bs(z0);
            }
    };

    auto do_wmu = [&](int cur, int ts) {
        if (cg < 2) {
            const unsigned short* za = zb[cur] + m16 * LDP + q * 8;
            f32x4 o = {};
            #pragma unroll
            for (int kk = 0; kk < 8; ++kk) {
                bf16x8 a = lds8(za + kk * 32);
                bf16x8 b = pk8(WMU_E + (size_t)(nto * 8 + kk) * 512 + lane8);
                o = MFMA16(a, b, o);
            }
            #pragma unroll
            for (int r = 0; r < 4; ++r) {
                float vv = o[r] + bmuv;
                const size_t oi = (size_t)(row0 + q * 4 + r) * (LSTEPS * CO)
                                + ts * CO + nto * 16 + m16;
                if constexpr (F32) ((float*)out)[oi] = vv;
                else               ((__hip_bfloat16*)out)[oi] = __float2bfloat16(vv);
            }
        }
    };

    auto do_rec = [&](int cur, int prv, bool hasGh) {
        f32x4 gh[3][2] = {};
        if (hasGh) {
            const unsigned short* ha0 = hb[prv] + m16 * LDP + q * 8;
            // 2-deep kk prefetch of the 6 b-frags (static after full unroll)
            bf16x8 pre[2][6];
            #pragma unroll
            for (int kk = 0; kk < 2; ++kk)
                #pragma unroll
                for (int g = 0; g < 3; ++g)
                    #pragma unroll
                    for (int j = 0; j < 2; ++j)
                        pre[kk][g * 2 + j] =
                            pk8(WHH_E + (size_t)(((cg * 3 + g) * 8 + kk) * 2 + j) * 512 + lane8);
            #pragma unroll
            for (int kk = 0; kk < 8; ++kk) {
                bf16x8 b00 = pre[kk & 1][0];
                bf16x8 b01 = pre[kk & 1][1];
                bf16x8 b10 = pre[kk & 1][2];
                bf16x8 b11 = pre[kk & 1][3];
                bf16x8 b20 = pre[kk & 1][4];
                bf16x8 b21 = pre[kk & 1][5];
                if (kk < 6) {
                    #pragma unroll
                    for (int g = 0; g < 3; ++g)
                        #pragma unroll
                        for (int j = 0; j < 2; ++j)
                            pre[kk & 1][g * 2 + j] =
                                pk8(WHH_E + (size_t)(((cg * 3 + g) * 8 + (kk + 2)) * 2 + j) * 512 + lane8);
                }
                bf16x8 fa0 = lds8(ha0 + kk * 32);
                gh[0][0] = MFMA16(fa0, b00, gh[0][0]);
                gh[0][1] = MFMA16(fa0, b01, gh[0][1]);
                gh[1][0] = MFMA16(fa0, b10, gh[1][0]);
                gh[1][1] = MFMA16(fa0, b11, gh[1][1]);
                gh[2][0] = MFMA16(fa0, b20, gh[2][0]);
                gh[2][1] = MFMA16(fa0, b21, gh[2][1]);
            }
        }
        #pragma unroll
        for (int j = 0; j < 2; ++j)
            #pragma unroll
            for (int r = 0; r < 4; ++r) {
                unsigned u = girz[j][r];
                float rr = sigm(bfu((unsigned short)(u & 0xffffu)) + gh[0][j][r]);
                float zz = sigm(bfu((unsigned short)(u >> 16)) + gh[1][j][r]);
                float nin = gin[j][r] + rr * (gh[2][j][r] + bhhn[j]);
                float nn = 2.0f * sigm(2.0f * nin) - 1.0f;   // tanh
                float hh = (1.0f - zz) * nn + zz * bfu(hs[j][r]);
                unsigned short hv = f2bs(hh);
                hs[j][r] = hv;
                const int idx = (q * 4 + r) * LDP + cc2[j];
                hb[cur][idx] = hv;
                float y = bfu(hv) * s2v[j] + t2v[j];
                y = (y >= 0.0f) ? y : a2v * y;
                yb[cur][idx] = f2bs(y);
            }
    };

    // ---- peeled schedule: 1 no-drain barrier/step, Wc/Wmu pipelined behind ----
    // t=0: recurrence only (gh = 0)
    do_rec(0, 1, false);
    bar_nodrain();
    // t=1: Wc on y(0); recurrence(1)
    do_wc(0);
    do_rec(1, 0, true);
    bar_nodrain();
    // steady: t=2..LSTEPS-1, straight-line body
    #pragma unroll 1
    for (int t = 2; t < LSTEPS; ++t) {
        const int cur = t & 1, prv = cur ^ 1;
        do_wc(prv);
        do_wmu(cur, t - 2);
        do_rec(cur, prv, true);
        bar_nodrain();
    }
    // t=LSTEPS: Wc on y(19); Wmu -> out(18)
    {
        const int cur = LSTEPS & 1, prv = cur ^ 1;
        do_wc(prv);
        do_wmu(cur, LSTEPS - 2);
        bar_nodrain();
    }
    // t=LSTEPS+1: Wmu -> out(19)
    {
        const int cur = (LSTEPS + 1) & 1;
        do_wmu(cur, LSTEPS - 1);
    }
}

__global__ __launch_bounds__(512, 2) void comm_fast(
    const void* hw, const void* blin,
    const void* g1, const void* be1, const void* m1, const void* v1, const void* a1,
    const void* bih, const void* bhh,
    const void* g2, const void* be2, const void* m2, const void* v2, const void* a2,
    const void* bc,
    const void* g3, const void* be3, const void* m3, const void* v3, const void* a3,
    const void* bmu,
    void* out)
{
    __shared__ __align__(16) unsigned short hb[2][BM * LDP];
    __shared__ __align__(16) unsigned short yb[2][BM * LDP];
    __shared__ __align__(16) unsigned short zb[2][BM * LDP];
    if (g_flag) {
        fast_pipe<true >(hw, blin, g1, be1, m1, v1, a1, bih, bhh,
                         g2, be2, m2, v2, a2, bc, g3, be3, m3, v3, a3, bmu,
                         out, hb, yb, zb);
    } else {
        fast_pipe<false>(hw, blin, g1, be1, m1, v1, a1, bih, bhh,
                         g2, be2, m2, v2, a2, bc, g3, be3, m3, v3, a3, bmu,
                         out, hb, yb, zb);
    }
}

extern "C" void kernel_launch(void* const* d_in, const int* in_sizes, int n_in,
                              void* d_out, int out_size, void* d_ws, size_t ws_size,
                              hipStream_t stream) {
    (void)in_sizes; (void)n_in; (void)out_size; (void)d_ws; (void)ws_size;
    detect_dtype<<<dim3(1), dim3(1), 0, stream>>>(d_in[6]);
    prepack<<<dim3(308), dim3(256), 0, stream>>>(
        d_in[1], d_in[8], d_in[9], d_in[17], d_in[24]);
    comm_fast<<<dim3(512), dim3(512), 0, stream>>>(
        d_in[0], d_in[2],
        d_in[3], d_in[4], d_in[5], d_in[6], d_in[7],
        d_in[10], d_in[11],
        d_in[12], d_in[13], d_in[14], d_in[15], d_in[16],
        d_in[18],
        d_in[19], d_in[20], d_in[21], d_in[22], d_in[23],
        d_in[25],
        d_out);
}

// Round 10
// 410.570 us; speedup vs baseline: 1.0751x; 1.0751x over previous
//
#include <hip/hip_runtime.h>
#include <hip/hip_bf16.h>

// Fused Comm_OUT pipeline, batch-row-parallel (GRU recurrence is per-row).
// Round-16: DEFERRED DRAIN. Model fixed by r0-r9: each barrier interval
// costs latency-floor + k*(issue work inside it) (r2: 2x work -> 1.63x;
// r3/r8: fewer/desynced intervals help; r1/r9: load count & vmcnt drain
// are nulls). Wc/Wmu/z-epilogue have NO dependence on the recurrence ->
// move them OUT of the 20 serial intervals: rec loop keeps only
// {gh, gates, h/y writes} (-35% issue in the serial chain); y(t) goes to
// a 4-deep LDS ring; every 4 steps a DRAIN does wc/wmu for 4 timesteps
// as dense pipelined MFMA mini-phases (wmu(k) || wc(k+1)), Wc frags
// reused 4x per load. LDS 67.6KB, still 2 independent domains/CU.
// 512 blocks x 512 threads (8 waves x 32 cols), BM=16.
// Runtime dtype detection (inputs fp32 or bf16) via g_flag.

typedef __attribute__((ext_vector_type(8))) short bf16x8;   // 8 x bf16 (4 VGPRs)
typedef __attribute__((ext_vector_type(4))) float f32x4;    // MFMA accumulator

#define MFMA16(a, b, c) __builtin_amdgcn_mfma_f32_16x16x32_bf16((a), (b), (c), 0, 0, 0)

// LDS-only barrier: no vmcnt drain (weights read-only; out never read back).
__device__ __forceinline__ void bar_nodrain() {
    asm volatile("s_waitcnt lgkmcnt(0)\n\ts_barrier" ::: "memory");
}

constexpr int F   = 640;
constexpr int H   = 256;
constexpr int LSTEPS = 20;
constexpr int CO  = 32;
constexpr int LDP = 264;   // padded bf16 row stride (16B-aligned rows)
constexpr int BM  = 16;    // rows per block (2 blocks/CU)

// packed-weight element offsets inside g_wpk (layout unchanged from r7)
constexpr size_t WHH_E  = 0;
constexpr size_t WIH_E  = 196608;
constexpr size_t WC_E   = 393216;
constexpr size_t WMU_E  = 458752;
constexpr size_t WLIN_E = 466944;
constexpr size_t PK_ELEMS = 630784;

__device__ __align__(16) unsigned short g_wpk[PK_ELEMS];
__device__ int g_flag;     // 1 = inputs are fp32

__device__ __forceinline__ float bf2f(__hip_bfloat16 x) { return __bfloat162float(x); }
__device__ __forceinline__ float bfu(unsigned short s) {
    __hip_bfloat16 h = *reinterpret_cast<__hip_bfloat16*>(&s);
    return __bfloat162float(h);
}
__device__ __forceinline__ unsigned short f2bs(float f) {
    __hip_bfloat16 h = __float2bfloat16(f);
    return *reinterpret_cast<unsigned short*>(&h);
}
__device__ __forceinline__ bf16x8 lds8(const unsigned short* p) {
    return *reinterpret_cast<const bf16x8*>(p);
}
__device__ __forceinline__ bf16x8 pk8(size_t eoff) {
    return *reinterpret_cast<const bf16x8*>(g_wpk + eoff);
}
__device__ __forceinline__ float sigm(float x) {
    return 1.0f / (1.0f + __expf(-x));
}
__device__ __forceinline__ unsigned pack2(float lo, float hi) {
    return (unsigned)f2bs(lo) | ((unsigned)f2bs(hi) << 16);
}

template<bool F32>
__device__ __forceinline__ bf16x8 g8(const void* base, size_t off) {
    if constexpr (!F32) {
        return *reinterpret_cast<const bf16x8*>((const __hip_bfloat16*)base + off);
    } else {
        const float* f = (const float*)base + off;
        float4 lo = *reinterpret_cast<const float4*>(f);
        float4 hi = *reinterpret_cast<const float4*>(f + 4);
        bf16x8 r;
        r[0] = (short)f2bs(lo.x); r[1] = (short)f2bs(lo.y);
        r[2] = (short)f2bs(lo.z); r[3] = (short)f2bs(lo.w);
        r[4] = (short)f2bs(hi.x); r[5] = (short)f2bs(hi.y);
        r[6] = (short)f2bs(hi.z); r[7] = (short)f2bs(hi.w);
        return r;
    }
}

template<bool F32>
__device__ __forceinline__ float ld1(const void* base, int i) {
    if constexpr (!F32) return bf2f(((const __hip_bfloat16*)base)[i]);
    else                return ((const float*)base)[i];
}

// ---------------- dtype detect: v1 (uniform[0.5,1.5]) ----------------
__global__ void detect_dtype(const void* v1) {
    const unsigned short* u = (const unsigned short*)v1;
    int f32 = 0;
    for (int i = 0; i < 8; ++i) {
        unsigned short s = u[i];
        __hip_bfloat16 h = *reinterpret_cast<__hip_bfloat16*>(&s);
        float v = __bfloat162float(h);
        if (!(v >= 0.25f && v <= 2.0f)) f32 = 1;
    }
    g_flag = f32;
}

// ---------------- weight pre-pack (fp32|bf16 -> bf16 fragment streams) ----------------
__device__ __forceinline__ unsigned short cvt1(const void* p, size_t i, bool f32) {
    if (f32) return f2bs(((const float*)p)[i]);
    return ((const unsigned short*)p)[i];
}

__global__ void prepack(const void* Wlin, const void* Wih, const void* Whh,
                        const void* Wc, const void* Wmu) {
    const bool f32 = (g_flag != 0);
    const int gid = blockIdx.x * 256 + threadIdx.x;
    const void* src;
    size_t dbase;
    int row, col0, ncols;
    if (gid < 24576) {                       // Whh [768,256]
        int idx = gid;
        int lane = idx & 63, j = (idx >> 6) & 1, kk = (idx >> 7) & 7;
        int t2 = idx >> 10, g = t2 % 3, w = t2 / 3;
        row = g * 256 + w * 32 + j * 16 + (lane & 15);
        col0 = kk * 32 + (lane >> 4) * 8;
        ncols = 256; src = Whh; dbase = WHH_E + (size_t)idx * 8;
    } else if (gid < 49152) {                // Wih [768,256]
        int idx = gid - 24576;
        int lane = idx & 63, j = (idx >> 6) & 1, kk = (idx >> 7) & 7;
        int t2 = idx >> 10, g = t2 % 3, w = t2 / 3;
        row = g * 256 + w * 32 + j * 16 + (lane & 15);
        col0 = kk * 32 + (lane >> 4) * 8;
        ncols = 256; src = Wih; dbase = WIH_E + (size_t)idx * 8;
    } else if (gid < 57344) {                // Wc [256,256]
        int idx = gid - 49152;
        int lane = idx & 63, j = (idx >> 6) & 1, kk = (idx >> 7) & 7, w = idx >> 10;
        row = w * 32 + j * 16 + (lane & 15);
        col0 = kk * 32 + (lane >> 4) * 8;
        ncols = 256; src = Wc; dbase = WC_E + (size_t)idx * 8;
    } else if (gid < 58368) {                // Wmu [32,256]
        int idx = gid - 57344;
        int lane = idx & 63, kk = (idx >> 6) & 7, w = idx >> 9;
        row = w * 16 + (lane & 15);
        col0 = kk * 32 + (lane >> 4) * 8;
        ncols = 256; src = Wmu; dbase = WMU_E + (size_t)idx * 8;
    } else if (gid < 78848) {                // Wlin [256,640]
        int idx = gid - 58368;
        int lane = idx & 63, j = (idx >> 6) & 1;
        int t1 = idx >> 7, kk = t1 % 20, w = t1 / 20;
        row = w * 32 + j * 16 + (lane & 15);
        col0 = kk * 32 + (lane >> 4) * 8;
        ncols = 640; src = Wlin; dbase = WLIN_E + (size_t)idx * 8;
    } else {
        return;
    }
    const size_t s0 = (size_t)row * ncols + col0;
    #pragma unroll
    for (int i = 0; i < 8; ++i) g_wpk[dbase + i] = cvt1(src, s0 + i, f32);
}

// ---------------- FAST PATH: BM=16, 8 waves, rec-only intervals + 4-step drains ----------------
template<bool F32>
__device__ __forceinline__ void fast_pipe(
    const void* hw, const void* blin,
    const void* g1, const void* be1, const void* m1, const void* v1, const void* a1,
    const void* bih, const void* bhh,
    const void* g2, const void* be2, const void* m2, const void* v2, const void* a2,
    const void* bc,
    const void* g3, const void* be3, const void* m3, const void* v3, const void* a3,
    const void* bmu,
    void* out,
    unsigned short (*hb)[BM * LDP],
    unsigned short (*yr)[BM * LDP],   // 4-deep y ring
    unsigned short (*zb)[BM * LDP])
{
    const int tid  = threadIdx.x;
    const int cg   = tid >> 6;        // wave = 32-col group, 0..7
    const int lane = tid & 63;
    const int m16  = lane & 15;
    const int q    = lane >> 4;
    const int row0 = blockIdx.x * BM;
    const int c0 = cg * 32 + m16;
    const int c1 = c0 + 16;
    const int cc2[2] = { c0, c1 };
    const size_t lane8 = (size_t)lane * 8;

    // persistent per-step params (folded)
    float s2v[2], t2v[2], s3v[2], t3f[2], bhhn[2];
    #pragma unroll
    for (int j = 0; j < 2; ++j) {
        const int cc = cc2[j];
        float s;
        s = ld1<F32>(g2, cc) * rsqrtf(ld1<F32>(v2, cc) + 1e-5f);
        s2v[j] = s; t2v[j] = ld1<F32>(be2, cc) - ld1<F32>(m2, cc) * s;
        s = ld1<F32>(g3, cc) * rsqrtf(ld1<F32>(v3, cc) + 1e-5f);
        s3v[j] = s;
        t3f[j] = (ld1<F32>(bc, cc) - ld1<F32>(m3, cc)) * s + ld1<F32>(be3, cc);
        bhhn[j] = ld1<F32>(bhh, 2 * H + cc);
    }
    const float a2v = ld1<F32>(a2, 0), a3v = ld1<F32>(a3, 0);

    // ---- Phase 1: x = prelu(bn1(rows @ Wlin^T + blin)) -> yr[3] (staging) ----
    {
        f32x4 xacc[2] = {};   // [j]
        #pragma unroll 5
        for (int kk = 0; kk < F / 32; ++kk) {
            bf16x8 fa0 = g8<F32>(hw, (size_t)(row0 + m16) * F + kk * 32 + q * 8);
            bf16x8 b0 = pk8(WLIN_E + (size_t)((cg * 20 + kk) * 2 + 0) * 512 + lane8);
            bf16x8 b1 = pk8(WLIN_E + (size_t)((cg * 20 + kk) * 2 + 1) * 512 + lane8);
            xacc[0] = MFMA16(fa0, b0, xacc[0]);
            xacc[1] = MFMA16(fa0, b1, xacc[1]);
        }
        #pragma unroll
        for (int j = 0; j < 2; ++j) {
            const int cc = cc2[j];
            float s = ld1<F32>(g1, cc) * rsqrtf(ld1<F32>(v1, cc) + 1e-5f);
            float t = ld1<F32>(be1, cc) - ld1<F32>(m1, cc) * s;
            float bl = ld1<F32>(blin, cc);
            float av = ld1<F32>(a1, 0);
            #pragma unroll
            for (int r = 0; r < 4; ++r) {
                float vv = (xacc[j][r] + bl) * s + t;
                vv = (vv >= 0.0f) ? vv : av * vv;
                yr[3][(q * 4 + r) * LDP + cc] = f2bs(vv);
            }
        }
    }
    __syncthreads();   // x visible in yr[3]

    // ---- Phase 2: gi = x @ Wih^T + biases; r/z packed bf16, n kept f32 ----
    unsigned girz[2][4];   // [j][r]: lo = r-gate, hi = z-gate pre-act
    f32x4 gin[2];          // [j]: n-gate pre-act
    {
        f32x4 ga[3][2] = {};
        const unsigned short* xa0 = yr[3] + m16 * LDP + q * 8;
        #pragma unroll
        for (int kk = 0; kk < 8; ++kk) {
            bf16x8 fa0 = lds8(xa0 + kk * 32);
            #pragma unroll
            for (int g = 0; g < 3; ++g) {
                bf16x8 b0 = pk8(WIH_E + (size_t)(((cg * 3 + g) * 8 + kk) * 2 + 0) * 512 + lane8);
                bf16x8 b1 = pk8(WIH_E + (size_t)(((cg * 3 + g) * 8 + kk) * 2 + 1) * 512 + lane8);
                ga[g][0] = MFMA16(fa0, b0, ga[g][0]);
                ga[g][1] = MFMA16(fa0, b1, ga[g][1]);
            }
        }
        #pragma unroll
        for (int j = 0; j < 2; ++j) {
            const float br = ld1<F32>(bih, 0 * H + cc2[j]) + ld1<F32>(bhh, 0 * H + cc2[j]);
            const float bz = ld1<F32>(bih, 1 * H + cc2[j]) + ld1<F32>(bhh, 1 * H + cc2[j]);
            const float bn = ld1<F32>(bih, 2 * H + cc2[j]);
            #pragma unroll
            for (int r = 0; r < 4; ++r)
                girz[j][r] = pack2(ga[0][j][r] + br, ga[1][j][r] + bz);
            #pragma unroll
            for (int r = 0; r < 4; ++r) gin[j][r] = ga[2][j][r] + bn;
        }
    }
    __syncthreads();   // x reads complete (yr[3] free for t=3)

    // ---- GRU loop state ----
    unsigned short hs[2][4];
    #pragma unroll
    for (int j = 0; j < 2; ++j)
        #pragma unroll
        for (int r = 0; r < 4; ++r) hs[j][r] = 0;   // bf16 +0.0

    const int nto = cg & 1;   // for cg<2: output col tile
    const float bmuv = (cg < 2) ? ld1<F32>(bmu, nto * 16 + m16) : 0.0f;

    // --- recurrence interval: gh + gates -> hb[cur], yr[yslot] ---
    auto do_rec = [&](int cur, int prv, int yslot, bool hasGh) {
        f32x4 gh[3][2] = {};
        if (hasGh) {
            const unsigned short* ha0 = hb[prv] + m16 * LDP + q * 8;
            // 2-deep kk prefetch of the 6 b-frags (static after full unroll)
            bf16x8 pre[2][6];
            #pragma unroll
            for (int kk = 0; kk < 2; ++kk)
                #pragma unroll
                for (int g = 0; g < 3; ++g)
                    #pragma unroll
                    for (int j = 0; j < 2; ++j)
                        pre[kk][g * 2 + j] =
                            pk8(WHH_E + (size_t)(((cg * 3 + g) * 8 + kk) * 2 + j) * 512 + lane8);
            #pragma unroll
            for (int kk = 0; kk < 8; ++kk) {
                bf16x8 b00 = pre[kk & 1][0];
                bf16x8 b01 = pre[kk & 1][1];
                bf16x8 b10 = pre[kk & 1][2];
                bf16x8 b11 = pre[kk & 1][3];
                bf16x8 b20 = pre[kk & 1][4];
                bf16x8 b21 = pre[kk & 1][5];
                if (kk < 6) {
                    #pragma unroll
                    for (int g = 0; g < 3; ++g)
                        #pragma unroll
                        for (int j = 0; j < 2; ++j)
                            pre[kk & 1][g * 2 + j] =
                                pk8(WHH_E + (size_t)(((cg * 3 + g) * 8 + (kk + 2)) * 2 + j) * 512 + lane8);
                }
                bf16x8 fa0 = lds8(ha0 + kk * 32);
                gh[0][0] = MFMA16(fa0, b00, gh[0][0]);
                gh[0][1] = MFMA16(fa0, b01, gh[0][1]);
                gh[1][0] = MFMA16(fa0, b10, gh[1][0]);
                gh[1][1] = MFMA16(fa0, b11, gh[1][1]);
                gh[2][0] = MFMA16(fa0, b20, gh[2][0]);
                gh[2][1] = MFMA16(fa0, b21, gh[2][1]);
            }
        }
        #pragma unroll
        for (int j = 0; j < 2; ++j)
            #pragma unroll
            for (int r = 0; r < 4; ++r) {
                unsigned u = girz[j][r];
                float rr = sigm(bfu((unsigned short)(u & 0xffffu)) + gh[0][j][r]);
                float zz = sigm(bfu((unsigned short)(u >> 16)) + gh[1][j][r]);
                float nin = gin[j][r] + rr * (gh[2][j][r] + bhhn[j]);
                float nn = 2.0f * sigm(2.0f * nin) - 1.0f;   // tanh
                float hh = (1.0f - zz) * nn + zz * bfu(hs[j][r]);
                unsigned short hv = f2bs(hh);
                hs[j][r] = hv;
                const int idx = (q * 4 + r) * LDP + cc2[j];
                hb[cur][idx] = hv;
                float y = bfu(hv) * s2v[j] + t2v[j];
                y = (y >= 0.0f) ? y : a2v * y;
                yr[yslot][idx] = f2bs(y);
            }
    };

    // --- drain pieces: wc(k): yr[k] -> zb[k&1];  wmu(k): zb[k&1] -> out(t) ---
    auto do_wc = [&](int yslot) {
        f32x4 w2[2] = {};
        const unsigned short* ya0 = yr[yslot] + m16 * LDP + q * 8;
        #pragma unroll
        for (int kk = 0; kk < 8; ++kk) {
            bf16x8 fa0 = lds8(ya0 + kk * 32);
            bf16x8 b0 = pk8(WC_E + (size_t)((cg * 8 + kk) * 2 + 0) * 512 + lane8);
            bf16x8 b1 = pk8(WC_E + (size_t)((cg * 8 + kk) * 2 + 1) * 512 + lane8);
            w2[0] = MFMA16(fa0, b0, w2[0]);
            w2[1] = MFMA16(fa0, b1, w2[1]);
        }
        #pragma unroll
        for (int j = 0; j < 2; ++j)
            #pragma unroll
            for (int r = 0; r < 4; ++r) {
                float z0 = w2[j][r] * s3v[j] + t3f[j];
                z0 = (z0 >= 0.0f) ? z0 : a3v * z0;
                zb[yslot & 1][(q * 4 + r) * LDP + cc2[j]] = f2bs(z0);
            }
    };

    auto do_wmu = [&](int zpar, int ts) {
        if (cg < 2) {
            const unsigned short* za = zb[zpar] + m16 * LDP + q * 8;
            f32x4 o = {};
            #pragma unroll
            for (int kk = 0; kk < 8; ++kk) {
                bf16x8 a = lds8(za + kk * 32);
                bf16x8 b = pk8(WMU_E + (size_t)(nto * 8 + kk) * 512 + lane8);
                o = MFMA16(a, b, o);
            }
            #pragma unroll
            for (int r = 0; r < 4; ++r) {
                float vv = o[r] + bmuv;
                const size_t oi = (size_t)(row0 + q * 4 + r) * (LSTEPS * CO)
                                + ts * CO + nto * 16 + m16;
                if constexpr (F32) ((float*)out)[oi] = vv;
                else               ((__hip_bfloat16*)out)[oi] = __float2bfloat16(vv);
            }
        }
    };

    // ---- main loop: 5 groups of {4 rec intervals + 1 pipelined drain} ----
    #pragma unroll 1
    for (int grp = 0; grp < 5; ++grp) {
        #pragma unroll
        for (int k = 0; k < 4; ++k) {
            // t = grp*4 + k;  cur = t&1 = k&1 (4 | t-parity aligns per group)
            do_rec(k & 1, (k & 1) ^ 1, k, (grp + k) > 0);
            bar_nodrain();
        }
        const int t0 = grp * 4;
        // drain: wmu(k) overlaps wc(k+1); zb parity alternates with k
        do_wc(0);
        bar_nodrain();
        do_wmu(0, t0 + 0); do_wc(1);
        bar_nodrain();
        do_wmu(1, t0 + 1); do_wc(2);
        bar_nodrain();
        do_wmu(0, t0 + 2); do_wc(3);
        bar_nodrain();
        do_wmu(1, t0 + 3);
        bar_nodrain();   // protects yr/zb reuse by next group's rec steps
    }
}

__global__ __launch_bounds__(512, 2) void comm_fast(
    const void* hw, const void* blin,
    const void* g1, const void* be1, const void* m1, const void* v1, const void* a1,
    const void* bih, const void* bhh,
    const void* g2, const void* be2, const void* m2, const void* v2, const void* a2,
    const void* bc,
    const void* g3, const void* be3, const void* m3, const void* v3, const void* a3,
    const void* bmu,
    void* out)
{
    __shared__ __align__(16) unsigned short hb[2][BM * LDP];
    __shared__ __align__(16) unsigned short yr[4][BM * LDP];
    __shared__ __align__(16) unsigned short zb[2][BM * LDP];
    if (g_flag) {
        fast_pipe<true >(hw, blin, g1, be1, m1, v1, a1, bih, bhh,
                         g2, be2, m2, v2, a2, bc, g3, be3, m3, v3, a3, bmu,
                         out, hb, yr, zb);
    } else {
        fast_pipe<false>(hw, blin, g1, be1, m1, v1, a1, bih, bhh,
                         g2, be2, m2, v2, a2, bc, g3, be3, m3, v3, a3, bmu,
                         out, hb, yr, zb);
    }
}

extern "C" void kernel_launch(void* const* d_in, const int* in_sizes, int n_in,
                              void* d_out, int out_size, void* d_ws, size_t ws_size,
                              hipStream_t stream) {
    (void)in_sizes; (void)n_in; (void)out_size; (void)d_ws; (void)ws_size;
    detect_dtype<<<dim3(1), dim3(1), 0, stream>>>(d_in[6]);
    prepack<<<dim3(308), dim3(256), 0, stream>>>(
        d_in[1], d_in[8], d_in[9], d_in[17], d_in[24]);
    comm_fast<<<dim3(512), dim3(512), 0, stream>>>(
        d_in[0], d_in[2],
        d_in[3], d_in[4], d_in[5], d_in[6], d_in[7],
        d_in[10], d_in[11],
        d_in[12], d_in[13], d_in[14], d_in[15], d_in[16],
        d_in[18],
        d_in[19], d_in[20], d_in[21], d_in[22], d_in[23],
        d_in[25],
        d_out);
}

// Round 11
// 354.689 us; speedup vs baseline: 1.2445x; 1.1576x over previous
//
#include <hip/hip_runtime.h>
#include <hip/hip_bf16.h>

// Fused Comm_OUT pipeline, batch-row-parallel (GRU recurrence is per-row).
// Round-17: ROLLED CODE / I$ attack. The unexplained 10-30x gap between
// per-interval critical path (~0.5us) and measured interval (~16us),
// insensitive to every data-path lever (r1 occupancy, r2 BW, r9 vmcnt,
// r5 load count), plus r2's code-size-proportional slowdown, points at
// INSTRUCTION CACHE THRASH: r10's unrolled group body (4 rec + 4 wc +
// 4 wmu copies) is ~40-50KB vs 32KB I$, re-fetched from L2 every group.
// Fix: same r10 schedule (20 rec intervals + 5 pipelined drains, no-drain
// barriers, 2 domains/CU) but ALL phases are shared rolled code: one
// do_rec with runtime cur/yslot (LDS addr arithmetic, no scratch),
// kk-loops at unroll 2, drains as rolled k-loops. Hot text ~10KB << I$.
// 512 blocks x 512 threads (8 waves x 32 cols), BM=16.
// Runtime dtype detection (inputs fp32 or bf16) via g_flag.

typedef __attribute__((ext_vector_type(8))) short bf16x8;   // 8 x bf16 (4 VGPRs)
typedef __attribute__((ext_vector_type(4))) float f32x4;    // MFMA accumulator

#define MFMA16(a, b, c) __builtin_amdgcn_mfma_f32_16x16x32_bf16((a), (b), (c), 0, 0, 0)

// LDS-only barrier: no vmcnt drain (weights read-only; out never read back).
__device__ __forceinline__ void bar_nodrain() {
    asm volatile("s_waitcnt lgkmcnt(0)\n\ts_barrier" ::: "memory");
}

constexpr int F   = 640;
constexpr int H   = 256;
constexpr int LSTEPS = 20;
constexpr int CO  = 32;
constexpr int LDP = 264;   // padded bf16 row stride (16B-aligned rows)
constexpr int BM  = 16;    // rows per block (2 blocks/CU)

// packed-weight element offsets inside g_wpk (layout unchanged from r7)
constexpr size_t WHH_E  = 0;
constexpr size_t WIH_E  = 196608;
constexpr size_t WC_E   = 393216;
constexpr size_t WMU_E  = 458752;
constexpr size_t WLIN_E = 466944;
constexpr size_t PK_ELEMS = 630784;

__device__ __align__(16) unsigned short g_wpk[PK_ELEMS];
__device__ int g_flag;     // 1 = inputs are fp32

__device__ __forceinline__ float bf2f(__hip_bfloat16 x) { return __bfloat162float(x); }
__device__ __forceinline__ float bfu(unsigned short s) {
    __hip_bfloat16 h = *reinterpret_cast<__hip_bfloat16*>(&s);
    return __bfloat162float(h);
}
__device__ __forceinline__ unsigned short f2bs(float f) {
    __hip_bfloat16 h = __float2bfloat16(f);
    return *reinterpret_cast<unsigned short*>(&h);
}
__device__ __forceinline__ bf16x8 lds8(const unsigned short* p) {
    return *reinterpret_cast<const bf16x8*>(p);
}
__device__ __forceinline__ bf16x8 pk8(size_t eoff) {
    return *reinterpret_cast<const bf16x8*>(g_wpk + eoff);
}
__device__ __forceinline__ float sigm(float x) {
    return 1.0f / (1.0f + __expf(-x));
}
__device__ __forceinline__ unsigned pack2(float lo, float hi) {
    return (unsigned)f2bs(lo) | ((unsigned)f2bs(hi) << 16);
}

template<bool F32>
__device__ __forceinline__ bf16x8 g8(const void* base, size_t off) {
    if constexpr (!F32) {
        return *reinterpret_cast<const bf16x8*>((const __hip_bfloat16*)base + off);
    } else {
        const float* f = (const float*)base + off;
        float4 lo = *reinterpret_cast<const float4*>(f);
        float4 hi = *reinterpret_cast<const float4*>(f + 4);
        bf16x8 r;
        r[0] = (short)f2bs(lo.x); r[1] = (short)f2bs(lo.y);
        r[2] = (short)f2bs(lo.z); r[3] = (short)f2bs(lo.w);
        r[4] = (short)f2bs(hi.x); r[5] = (short)f2bs(hi.y);
        r[6] = (short)f2bs(hi.z); r[7] = (short)f2bs(hi.w);
        return r;
    }
}

template<bool F32>
__device__ __forceinline__ float ld1(const void* base, int i) {
    if constexpr (!F32) return bf2f(((const __hip_bfloat16*)base)[i]);
    else                return ((const float*)base)[i];
}

// ---------------- dtype detect: v1 (uniform[0.5,1.5]) ----------------
__global__ void detect_dtype(const void* v1) {
    const unsigned short* u = (const unsigned short*)v1;
    int f32 = 0;
    for (int i = 0; i < 8; ++i) {
        unsigned short s = u[i];
        __hip_bfloat16 h = *reinterpret_cast<__hip_bfloat16*>(&s);
        float v = __bfloat162float(h);
        if (!(v >= 0.25f && v <= 2.0f)) f32 = 1;
    }
    g_flag = f32;
}

// ---------------- weight pre-pack (fp32|bf16 -> bf16 fragment streams) ----------------
__device__ __forceinline__ unsigned short cvt1(const void* p, size_t i, bool f32) {
    if (f32) return f2bs(((const float*)p)[i]);
    return ((const unsigned short*)p)[i];
}

__global__ void prepack(const void* Wlin, const void* Wih, const void* Whh,
                        const void* Wc, const void* Wmu) {
    const bool f32 = (g_flag != 0);
    const int gid = blockIdx.x * 256 + threadIdx.x;
    const void* src;
    size_t dbase;
    int row, col0, ncols;
    if (gid < 24576) {                       // Whh [768,256]
        int idx = gid;
        int lane = idx & 63, j = (idx >> 6) & 1, kk = (idx >> 7) & 7;
        int t2 = idx >> 10, g = t2 % 3, w = t2 / 3;
        row = g * 256 + w * 32 + j * 16 + (lane & 15);
        col0 = kk * 32 + (lane >> 4) * 8;
        ncols = 256; src = Whh; dbase = WHH_E + (size_t)idx * 8;
    } else if (gid < 49152) {                // Wih [768,256]
        int idx = gid - 24576;
        int lane = idx & 63, j = (idx >> 6) & 1, kk = (idx >> 7) & 7;
        int t2 = idx >> 10, g = t2 % 3, w = t2 / 3;
        row = g * 256 + w * 32 + j * 16 + (lane & 15);
        col0 = kk * 32 + (lane >> 4) * 8;
        ncols = 256; src = Wih; dbase = WIH_E + (size_t)idx * 8;
    } else if (gid < 57344) {                // Wc [256,256]
        int idx = gid - 49152;
        int lane = idx & 63, j = (idx >> 6) & 1, kk = (idx >> 7) & 7, w = idx >> 10;
        row = w * 32 + j * 16 + (lane & 15);
        col0 = kk * 32 + (lane >> 4) * 8;
        ncols = 256; src = Wc; dbase = WC_E + (size_t)idx * 8;
    } else if (gid < 58368) {                // Wmu [32,256]
        int idx = gid - 57344;
        int lane = idx & 63, kk = (idx >> 6) & 7, w = idx >> 9;
        row = w * 16 + (lane & 15);
        col0 = kk * 32 + (lane >> 4) * 8;
        ncols = 256; src = Wmu; dbase = WMU_E + (size_t)idx * 8;
    } else if (gid < 78848) {                // Wlin [256,640]
        int idx = gid - 58368;
        int lane = idx & 63, j = (idx >> 6) & 1;
        int t1 = idx >> 7, kk = t1 % 20, w = t1 / 20;
        row = w * 32 + j * 16 + (lane & 15);
        col0 = kk * 32 + (lane >> 4) * 8;
        ncols = 640; src = Wlin; dbase = WLIN_E + (size_t)idx * 8;
    } else {
        return;
    }
    const size_t s0 = (size_t)row * ncols + col0;
    #pragma unroll
    for (int i = 0; i < 8; ++i) g_wpk[dbase + i] = cvt1(src, s0 + i, f32);
}

// ---------------- FAST PATH: BM=16, 8 waves, ROLLED code, r10 schedule ----------------
template<bool F32>
__device__ __forceinline__ void fast_pipe(
    const void* hw, const void* blin,
    const void* g1, const void* be1, const void* m1, const void* v1, const void* a1,
    const void* bih, const void* bhh,
    const void* g2, const void* be2, const void* m2, const void* v2, const void* a2,
    const void* bc,
    const void* g3, const void* be3, const void* m3, const void* v3, const void* a3,
    const void* bmu,
    void* out,
    unsigned short (*hb)[BM * LDP],
    unsigned short (*yr)[BM * LDP],   // 4-deep y ring
    unsigned short (*zb)[BM * LDP])
{
    const int tid  = threadIdx.x;
    const int cg   = tid >> 6;        // wave = 32-col group, 0..7
    const int lane = tid & 63;
    const int m16  = lane & 15;
    const int q    = lane >> 4;
    const int row0 = blockIdx.x * BM;
    const int c0 = cg * 32 + m16;
    const int c1 = c0 + 16;
    const int cc2[2] = { c0, c1 };
    const size_t lane8 = (size_t)lane * 8;

    // persistent per-step params (folded)
    float s2v[2], t2v[2], s3v[2], t3f[2], bhhn[2];
    #pragma unroll
    for (int j = 0; j < 2; ++j) {
        const int cc = cc2[j];
        float s;
        s = ld1<F32>(g2, cc) * rsqrtf(ld1<F32>(v2, cc) + 1e-5f);
        s2v[j] = s; t2v[j] = ld1<F32>(be2, cc) - ld1<F32>(m2, cc) * s;
        s = ld1<F32>(g3, cc) * rsqrtf(ld1<F32>(v3, cc) + 1e-5f);
        s3v[j] = s;
        t3f[j] = (ld1<F32>(bc, cc) - ld1<F32>(m3, cc)) * s + ld1<F32>(be3, cc);
        bhhn[j] = ld1<F32>(bhh, 2 * H + cc);
    }
    const float a2v = ld1<F32>(a2, 0), a3v = ld1<F32>(a3, 0);

    // ---- Phase 1 (rolled): x = prelu(bn1(rows @ Wlin^T + blin)) -> yr[3] ----
    {
        f32x4 xacc[2] = {};   // [j]
        const size_t wlbase = WLIN_E + (size_t)cg * 20 * 2 * 512 + lane8;
        #pragma unroll 2
        for (int kk = 0; kk < F / 32; ++kk) {
            bf16x8 fa0 = g8<F32>(hw, (size_t)(row0 + m16) * F + kk * 32 + q * 8);
            bf16x8 b0 = pk8(wlbase + (size_t)(kk * 2 + 0) * 512);
            bf16x8 b1 = pk8(wlbase + (size_t)(kk * 2 + 1) * 512);
            xacc[0] = MFMA16(fa0, b0, xacc[0]);
            xacc[1] = MFMA16(fa0, b1, xacc[1]);
        }
        #pragma unroll
        for (int j = 0; j < 2; ++j) {
            const int cc = cc2[j];
            float s = ld1<F32>(g1, cc) * rsqrtf(ld1<F32>(v1, cc) + 1e-5f);
            float t = ld1<F32>(be1, cc) - ld1<F32>(m1, cc) * s;
            float bl = ld1<F32>(blin, cc);
            float av = ld1<F32>(a1, 0);
            #pragma unroll
            for (int r = 0; r < 4; ++r) {
                float vv = (xacc[j][r] + bl) * s + t;
                vv = (vv >= 0.0f) ? vv : av * vv;
                yr[3][(q * 4 + r) * LDP + cc] = f2bs(vv);
            }
        }
    }
    __syncthreads();   // x visible in yr[3]

    // ---- Phase 2 (rolled): gi = x @ Wih^T + biases ----
    unsigned girz[2][4];   // [j][r]: lo = r-gate, hi = z-gate pre-act
    f32x4 gin[2];          // [j]: n-gate pre-act
    {
        f32x4 ga[3][2] = {};
        const unsigned short* xa0 = yr[3] + m16 * LDP + q * 8;
        const size_t wibase = WIH_E + (size_t)cg * 3 * 8 * 2 * 512 + lane8;
        #pragma unroll 2
        for (int kk = 0; kk < 8; ++kk) {
            bf16x8 fa0 = lds8(xa0 + kk * 32);
            #pragma unroll
            for (int g = 0; g < 3; ++g) {
                bf16x8 b0 = pk8(wibase + (size_t)((g * 8 + kk) * 2 + 0) * 512);
                bf16x8 b1 = pk8(wibase + (size_t)((g * 8 + kk) * 2 + 1) * 512);
                ga[g][0] = MFMA16(fa0, b0, ga[g][0]);
                ga[g][1] = MFMA16(fa0, b1, ga[g][1]);
            }
        }
        #pragma unroll
        for (int j = 0; j < 2; ++j) {
            const float br = ld1<F32>(bih, 0 * H + cc2[j]) + ld1<F32>(bhh, 0 * H + cc2[j]);
            const float bz = ld1<F32>(bih, 1 * H + cc2[j]) + ld1<F32>(bhh, 1 * H + cc2[j]);
            const float bn = ld1<F32>(bih, 2 * H + cc2[j]);
            #pragma unroll
            for (int r = 0; r < 4; ++r)
                girz[j][r] = pack2(ga[0][j][r] + br, ga[1][j][r] + bz);
            #pragma unroll
            for (int r = 0; r < 4; ++r) gin[j][r] = ga[2][j][r] + bn;
        }
    }
    __syncthreads();   // x reads complete (yr[3] free for t=3)

    // ---- GRU loop state ----
    unsigned short hs[2][4];
    #pragma unroll
    for (int j = 0; j < 2; ++j)
        #pragma unroll
        for (int r = 0; r < 4; ++r) hs[j][r] = 0;   // bf16 +0.0

    const int nto = cg & 1;   // for cg<2: output col tile
    const float bmuv = (cg < 2) ? ld1<F32>(bmu, nto * 16 + m16) : 0.0f;

    // --- recurrence interval (rolled kk): gh + gates -> hb[cur], yr[yslot] ---
    const size_t whbase = WHH_E + (size_t)cg * 3 * 8 * 2 * 512 + lane8;
    auto do_rec = [&](int cur, int prv, int yslot, bool hasGh) {
        f32x4 gh[3][2] = {};
        if (hasGh) {
            const unsigned short* ha0 = hb[prv] + m16 * LDP + q * 8;
            #pragma unroll 2
            for (int kk = 0; kk < 8; ++kk) {
                bf16x8 fa0 = lds8(ha0 + kk * 32);
                #pragma unroll
                for (int g = 0; g < 3; ++g) {
                    bf16x8 b0 = pk8(whbase + (size_t)((g * 8 + kk) * 2 + 0) * 512);
                    bf16x8 b1 = pk8(whbase + (size_t)((g * 8 + kk) * 2 + 1) * 512);
                    gh[g][0] = MFMA16(fa0, b0, gh[g][0]);
                    gh[g][1] = MFMA16(fa0, b1, gh[g][1]);
                }
            }
        }
        unsigned short* yw = yr[yslot];
        unsigned short* hw2 = hb[cur];
        #pragma unroll
        for (int j = 0; j < 2; ++j)
            #pragma unroll
            for (int r = 0; r < 4; ++r) {
                unsigned u = girz[j][r];
                float rr = sigm(bfu((unsigned short)(u & 0xffffu)) + gh[0][j][r]);
                float zz = sigm(bfu((unsigned short)(u >> 16)) + gh[1][j][r]);
                float nin = gin[j][r] + rr * (gh[2][j][r] + bhhn[j]);
                float nn = 2.0f * sigm(2.0f * nin) - 1.0f;   // tanh
                float hh = (1.0f - zz) * nn + zz * bfu(hs[j][r]);
                unsigned short hv = f2bs(hh);
                hs[j][r] = hv;
                const int idx = (q * 4 + r) * LDP + cc2[j];
                hw2[idx] = hv;
                float y = bfu(hv) * s2v[j] + t2v[j];
                y = (y >= 0.0f) ? y : a2v * y;
                yw[idx] = f2bs(y);
            }
    };

    // --- drain pieces (rolled kk): wc(k): yr[k] -> zb[k&1]; wmu: zb -> out ---
    const size_t wcbase = WC_E + (size_t)cg * 8 * 2 * 512 + lane8;
    auto do_wc = [&](int ys) {
        f32x4 w2[2] = {};
        const unsigned short* ya0 = yr[ys] + m16 * LDP + q * 8;
        #pragma unroll 2
        for (int kk = 0; kk < 8; ++kk) {
            bf16x8 fa0 = lds8(ya0 + kk * 32);
            bf16x8 b0 = pk8(wcbase + (size_t)(kk * 2 + 0) * 512);
            bf16x8 b1 = pk8(wcbase + (size_t)(kk * 2 + 1) * 512);
            w2[0] = MFMA16(fa0, b0, w2[0]);
            w2[1] = MFMA16(fa0, b1, w2[1]);
        }
        unsigned short* zw = zb[ys & 1];
        #pragma unroll
        for (int j = 0; j < 2; ++j)
            #pragma unroll
            for (int r = 0; r < 4; ++r) {
                float z0 = w2[j][r] * s3v[j] + t3f[j];
                z0 = (z0 >= 0.0f) ? z0 : a3v * z0;
                zw[(q * 4 + r) * LDP + cc2[j]] = f2bs(z0);
            }
    };

    auto do_wmu = [&](int zpar, int ts) {
        if (cg < 2) {
            const unsigned short* za = zb[zpar] + m16 * LDP + q * 8;
            f32x4 o = {};
            #pragma unroll 2
            for (int kk = 0; kk < 8; ++kk) {
                bf16x8 a = lds8(za + kk * 32);
                bf16x8 b = pk8(WMU_E + (size_t)(nto * 8 + kk) * 512 + lane8);
                o = MFMA16(a, b, o);
            }
            #pragma unroll
            for (int r = 0; r < 4; ++r) {
                float vv = o[r] + bmuv;
                const size_t oi = (size_t)(row0 + q * 4 + r) * (LSTEPS * CO)
                                + (size_t)ts * CO + nto * 16 + m16;
                if constexpr (F32) ((float*)out)[oi] = vv;
                else               ((__hip_bfloat16*)out)[oi] = __float2bfloat16(vv);
            }
        }
    };

    // ---- main loop (rolled): rec every step; pipelined drain every 4 steps ----
    #pragma unroll 1
    for (int t = 0; t < LSTEPS; ++t) {
        do_rec(t & 1, (t & 1) ^ 1, t & 3, t > 0);
        bar_nodrain();
        if ((t & 3) == 3) {
            const int t0 = t - 3;
            do_wc(0);
            bar_nodrain();
            #pragma unroll 1
            for (int k = 1; k < 4; ++k) {
                do_wmu((k - 1) & 1, t0 + k - 1);
                do_wc(k);
                bar_nodrain();
            }
            do_wmu(1, t0 + 3);
            bar_nodrain();
        }
    }
}

__global__ __launch_bounds__(512, 2) void comm_fast(
    const void* hw, const void* blin,
    const void* g1, const void* be1, const void* m1, const void* v1, const void* a1,
    const void* bih, const void* bhh,
    const void* g2, const void* be2, const void* m2, const void* v2, const void* a2,
    const void* bc,
    const void* g3, const void* be3, const void* m3, const void* v3, const void* a3,
    const void* bmu,
    void* out)
{
    __shared__ __align__(16) unsigned short hb[2][BM * LDP];
    __shared__ __align__(16) unsigned short yr[4][BM * LDP];
    __shared__ __align__(16) unsigned short zb[2][BM * LDP];
    if (g_flag) {
        fast_pipe<true >(hw, blin, g1, be1, m1, v1, a1, bih, bhh,
                         g2, be2, m2, v2, a2, bc, g3, be3, m3, v3, a3, bmu,
                         out, hb, yr, zb);
    } else {
        fast_pipe<false>(hw, blin, g1, be1, m1, v1, a1, bih, bhh,
                         g2, be2, m2, v2, a2, bc, g3, be3, m3, v3, a3, bmu,
                         out, hb, yr, zb);
    }
}

extern "C" void kernel_launch(void* const* d_in, const int* in_sizes, int n_in,
                              void* d_out, int out_size, void* d_ws, size_t ws_size,
                              hipStream_t stream) {
    (void)in_sizes; (void)n_in; (void)out_size; (void)d_ws; (void)ws_size;
    detect_dtype<<<dim3(1), dim3(1), 0, stream>>>(d_in[6]);
    prepack<<<dim3(308), dim3(256), 0, stream>>>(
        d_in[1], d_in[8], d_in[9], d_in[17], d_in[24]);
    comm_fast<<<dim3(512), dim3(512), 0, stream>>>(
        d_in[0], d_in[2],
        d_in[3], d_in[4], d_in[5], d_in[6], d_in[7],
        d_in[10], d_in[11],
        d_in[12], d_in[13], d_in[14], d_in[15], d_in[16],
        d_in[18],
        d_in[19], d_in[20], d_in[21], d_in[22], d_in[23],
        d_in[25],
        d_out);
}